// Round 9
// baseline (246.441 us; speedup 1.0000x reference)
//
#include <hip/hip_runtime.h>
#include <hip/hip_fp16.h>

#define NN 50000
#define NE 800000
#define D  96
#define NB_SCAN 196   // ceil(NN/256)
#define N4 (NN * D / 4)
#define CB4 ((N4 + 255) / 256)
#define WFRAG_BLKS 5  // ceil(18*64/256)
#define ECAP 64                     // fixed slots per row (Poisson(16): P(deg>64)~e^-50)
#define EMAX (NN * ECAP)            // 3.2M words, 12.8 MB
#define EZ4  (EMAX / 4)             // 800000 v4u words
#define EZB  (EZ4 / 256)            // 3125

typedef unsigned int   uint32;
typedef unsigned short uint16;
typedef short  v8s __attribute__((ext_vector_type(8)));  // 8 bf16 (4 VGPRs)
typedef float  v4f __attribute__((ext_vector_type(4)));  // MFMA accumulator
typedef unsigned int v2u __attribute__((ext_vector_type(2)));
typedef unsigned int v4u __attribute__((ext_vector_type(4)));
typedef float v2f __attribute__((ext_vector_type(2)));

__device__ inline uint16 f32_to_bf16(float f) {          // round-nearest-even
    uint32 u = __float_as_uint(f);
    u += 0x7FFF + ((u >> 16) & 1);
    return (uint16)(u >> 16);
}

__device__ inline __half2 u2h(uint32 u) { union { uint32 u; __half2 h; } c; c.u = u; return c.h; }
__device__ inline uint32 h2u(__half2 h) { union { uint32 u; __half2 h; } c; c.h = h; return c.u; }

// ---- fused prep: H->f16 | zero counts | W->B-frag (bf16) | zero edges ----
// Full edge-array zero makes ALL unused slots legal zero-edges (col 0, val 0),
// which the spmm passes exploit with uniform 32-wide rounds (no tails).
__global__ void prep(const float4* __restrict__ H, ushort4* __restrict__ Hh,
                     const float* __restrict__ W, uint16* __restrict__ Wfrag,
                     int* __restrict__ counts, v4u* __restrict__ edges4) {
    int b = blockIdx.x;
    int t = threadIdx.x;
    if (b < CB4) {
        int i = b * 256 + t;
        if (i < N4) {
            float4 v = H[i];
            ushort4 o;
            o.x = __half_raw(__float2half(v.x)).x;
            o.y = __half_raw(__float2half(v.y)).x;
            o.z = __half_raw(__float2half(v.z)).x;
            o.w = __half_raw(__float2half(v.w)).x;
            Hh[i] = o;
        }
    } else if (b < CB4 + NB_SCAN) {
        int i = (b - CB4) * 256 + t;
        if (i < NN) counts[i] = 0;
    } else if (b < CB4 + NB_SCAN + WFRAG_BLKS) {
        int idx = (b - CB4 - NB_SCAN) * 256 + t;   // 0..1151 = bt*64+lane
        if (idx < 18 * 64) {
            int bt = idx >> 6, lane = idx & 63;
            int nt = bt / 3, kc = bt % 3;
            int col = nt * 16 + (lane & 15);
            int kbase = kc * 32 + (lane >> 4) * 8;
            uint16 tmp[8];
            #pragma unroll
            for (int j = 0; j < 8; ++j) tmp[j] = f32_to_bf16(W[(kbase + j) * D + col]);
            uint32* dst = (uint32*)(Wfrag + ((size_t)bt * 64 + lane) * 8);
            const uint32* src = (const uint32*)tmp;
            #pragma unroll
            for (int j = 0; j < 4; ++j) dst[j] = src[j];
        }
    } else {
        int i = (b - CB4 - NB_SCAN - WFRAG_BLKS) * 256 + t;
        if (i < EZ4) edges4[i] = (v4u){0u, 0u, 0u, 0u};
    }
}

// ---- merged CSR build: slot = atomicAdd(count) and DIRECT edge write -------
// Fixed stride ECAP=64 per row: no scan, no row_ptr, no slot array.
// edge word = col (low 16) | f16(val) (high 16). 2 edges/thread.
__global__ void build_edges(const int* __restrict__ rows, const int* __restrict__ cols,
                            const float* __restrict__ vals, int* __restrict__ counts,
                            uint32* __restrict__ edges) {
    int base = (blockIdx.x * blockDim.x + threadIdx.x) * 2;
    if (base < NE) {
        v2u rr = *(const v2u*)(rows + base);
        v2u cc = *(const v2u*)(cols + base);
        v2f vv = *(const v2f*)(vals + base);
        __half_raw h0 = __half_raw(__float2half(vv.x));
        __half_raw h1 = __half_raw(__float2half(vv.y));
        int s0 = atomicAdd(&counts[rr.x], 1);
        edges[((uint32)rr.x << 6) + s0] = (cc.x & 0xFFFF) | ((uint32)h0.x << 16);
        int s1 = atomicAdd(&counts[rr.y], 1);
        edges[((uint32)rr.y << 6) + s1] = (cc.y & 0xFFFF) | ((uint32)h1.x << 16);
    }
}

// ---- f16 gather core, UNIFORM 32-wide rounds -------------------------------
// Row work padded to a multiple of 32; pad slots are exact zero-edges (whole
// array pre-zeroed), so ~97% of rows (deg<=32) finish in ONE latency round
// with 32 gathers in flight (sched_barrier pins loads above consumers).
// Zero-pad gathers all hit row 0 -> L1-resident broadcast, effectively free.
__device__ inline void gather_f16(const uint32* __restrict__ edges, int s, int e,
                                  const char* __restrict__ lanep,
                                  __half2& a01, __half2& a23) {
    a01 = u2h(0u); a23 = u2h(0u);
    for (int i = s; i < e; i += 32) {
        v4u E[8];
        #pragma unroll
        for (int q = 0; q < 8; ++q) E[q] = *(const v4u*)(edges + i + q * 4);
        uint32 ee[32];
        #pragma unroll
        for (int q = 0; q < 8; ++q) {
            ee[q*4+0] = E[q].x; ee[q*4+1] = E[q].y;
            ee[q*4+2] = E[q].z; ee[q*4+3] = E[q].w;
        }
        v2u xx[32];
        #pragma unroll
        for (int j = 0; j < 32; ++j)
            xx[j] = *(const v2u*)(lanep + (ee[j] & 0xFFFFu) * 192u);
        __builtin_amdgcn_sched_barrier(0);   // all 32 gathers issued first
        #pragma unroll
        for (int j = 0; j < 32; ++j) {
            __half2 vv = u2h(__builtin_amdgcn_perm(ee[j], ee[j], 0x03020302u));
            a01 = __hfma2(vv, u2h(xx[j].x), a01);
            a23 = __hfma2(vv, u2h(xx[j].y), a23);
        }
    }
}

// ---- pure SpMM: Yh = f16( sum val * Xh[col] ) ------------------------------
__global__ void spmm(const int* __restrict__ counts, const uint32* __restrict__ edges,
                     const uint16* __restrict__ Xh, uint16* __restrict__ Yh) {
    int tid  = threadIdx.x;
    int lane = tid & 31;
    int g    = tid >> 5;
    int r = blockIdx.x * 8 + g;
    if (r >= NN) return;
    if (lane >= 24) return;

    const char* lanep = (const char*)Xh + lane * 8;

    int s = r << 6;                           // fixed stride ECAP=64
    int e = s + ((counts[r] + 31) & ~31);     // 0, 32 or 64
    __half2 a01, a23;
    gather_f16(edges, s, e, lanep, a01, a23);

    v2u o; o.x = h2u(a01); o.y = h2u(a23);
    *((v2u*)(Yh + (size_t)r * D) + lane) = o;
}

// ---- fused pass 3: Sb = bf16( 12*U1 - 40*U2 + 32 * P U2 ) ------------------
__global__ void spmm_fuse(const int* __restrict__ counts, const uint32* __restrict__ edges,
                          const uint16* __restrict__ U1, const uint16* __restrict__ U2,
                          uint16* __restrict__ Sb) {
    int tid  = threadIdx.x;
    int lane = tid & 31;
    int g    = tid >> 5;
    int r = blockIdx.x * 8 + g;
    if (r >= NN) return;
    if (lane >= 24) return;

    const char* lanep = (const char*)U2 + lane * 8;

    int s = r << 6;
    int e = s + ((counts[r] + 31) & ~31);
    __half2 a01, a23;
    gather_f16(edges, s, e, lanep, a01, a23);

    v2u w1 = *((const v2u*)(U1 + (size_t)r * D) + lane);
    v2u w2 = *(const v2u*)(lanep + (uint32)r * 192u);
    float2 ax = __half22float2(a01),      ay = __half22float2(a23);
    float2 p01 = __half22float2(u2h(w1.x)), p23 = __half22float2(u2h(w1.y));
    float2 q01 = __half22float2(u2h(w2.x)), q23 = __half22float2(u2h(w2.y));

    float s0 = 12.f*p01.x - 40.f*q01.x + 32.f*ax.x;
    float s1 = 12.f*p01.y - 40.f*q01.y + 32.f*ax.y;
    float s2 = 12.f*p23.x - 40.f*q23.x + 32.f*ay.x;
    float s3 = 12.f*p23.y - 40.f*q23.y + 32.f*ay.y;

    v2u o;
    o.x = (uint32)f32_to_bf16(s0) | ((uint32)f32_to_bf16(s1) << 16);
    o.y = (uint32)f32_to_bf16(s2) | ((uint32)f32_to_bf16(s3) << 16);
    *((v2u*)(Sb + (size_t)r * D) + lane) = o;
}

// ---- out = Sb @ W + bias via MFMA; one wave per 16-row strip (grid-stride) --
__global__ void mfma_gemm(const uint16* __restrict__ Sb, const uint16* __restrict__ Wfrag,
                          const float* __restrict__ bias, float* __restrict__ out) {
    int tid   = threadIdx.x;
    int lane  = tid & 63;
    int wv    = blockIdx.x * (blockDim.x >> 6) + (tid >> 6);
    int nwv   = gridDim.x * (blockDim.x >> 6);
    int col   = lane & 15;
    int quad  = lane >> 4;

    v8s wf[6][3];
    #pragma unroll
    for (int nt = 0; nt < 6; ++nt)
        #pragma unroll
        for (int kc = 0; kc < 3; ++kc)
            wf[nt][kc] = ((const v8s*)Wfrag)[(nt * 3 + kc) * 64 + lane];

    float bi[6];
    #pragma unroll
    for (int nt = 0; nt < 6; ++nt) bi[nt] = bias[nt * 16 + col];

    for (int s = wv; s < NN / 16; s += nwv) {
        int r0 = s * 16;
        const uint16* arow = Sb + (size_t)(r0 + col) * D + quad * 8;
        v8s a0 = *((const v8s*)(arow));
        v8s a1 = *((const v8s*)(arow + 32));
        v8s a2 = *((const v8s*)(arow + 64));
        v4f acc[6];
        #pragma unroll
        for (int nt = 0; nt < 6; ++nt) {
            v4f c = {0.f, 0.f, 0.f, 0.f};
            c = __builtin_amdgcn_mfma_f32_16x16x32_bf16(a0, wf[nt][0], c, 0, 0, 0);
            c = __builtin_amdgcn_mfma_f32_16x16x32_bf16(a1, wf[nt][1], c, 0, 0, 0);
            c = __builtin_amdgcn_mfma_f32_16x16x32_bf16(a2, wf[nt][2], c, 0, 0, 0);
            acc[nt] = c;
        }
        #pragma unroll
        for (int nt = 0; nt < 6; ++nt) {
            float* o = out + (size_t)(r0 + quad * 4) * D + nt * 16 + col;
            __builtin_nontemporal_store(acc[nt][0] + bi[nt], o + 0 * D);
            __builtin_nontemporal_store(acc[nt][1] + bi[nt], o + 1 * D);
            __builtin_nontemporal_store(acc[nt][2] + bi[nt], o + 2 * D);
            __builtin_nontemporal_store(acc[nt][3] + bi[nt], o + 3 * D);
        }
    }
}

extern "C" void kernel_launch(void* const* d_in, const int* in_sizes, int n_in,
                              void* d_out, int out_size, void* d_ws, size_t ws_size,
                              hipStream_t stream) {
    const int*   rows = (const int*)d_in[0];
    const int*   cols = (const int*)d_in[1];
    const float* vals = (const float*)d_in[2];
    const float* H    = (const float*)d_in[3];
    const float* W    = (const float*)d_in[4];
    const float* bias = (const float*)d_in[5];
    float* out = (float*)d_out;

    char* ws = (char*)d_ws;
    uint16* Hh       = (uint16*)ws;  ws += (size_t)NN * D * 2;   // 9.6 MB (f16)
    uint16* U1h      = (uint16*)ws;  ws += (size_t)NN * D * 2;   // f16
    uint16* U2h      = (uint16*)ws;  ws += (size_t)NN * D * 2;   // f16
    uint16* Sb       = (uint16*)ws;  ws += (size_t)NN * D * 2;   // bf16 (MFMA input)
    uint32* edges    = (uint32*)ws;  ws += (size_t)EMAX * 4;     // 12.8 MB fixed-stride
    uint16* Wfrag    = (uint16*)ws;  ws += (size_t)18 * 64 * 8 * 2;
    int*    counts   = (int*)ws;     ws += (size_t)NN * 4;

    const int eb2 = (NE / 2 + 255) / 256;   // 2 edges/thread

    // 7 dispatches total (was 9): no scan, no separate fill, no slot array.
    prep<<<CB4 + NB_SCAN + WFRAG_BLKS + EZB, 256, 0, stream>>>(
        (const float4*)H, (ushort4*)Hh, W, Wfrag, counts, (v4u*)edges);
    build_edges<<<eb2, 256, 0, stream>>>(rows, cols, vals, counts, edges);

    const int sb = (NN + 7) / 8;   // 6250 blocks, 8 rows each

    // U1 = P H,  U2 = P U1,  Sb = 12U1 - 40U2 + 32 P U2  (= T0+T1+T2+T3)
    spmm<<<sb, 256, 0, stream>>>(counts, edges, Hh,  U1h);
    spmm<<<sb, 256, 0, stream>>>(counts, edges, U1h, U2h);
    spmm_fuse<<<sb, 256, 0, stream>>>(counts, edges, U1h, U2h, Sb);
    // out = Sb @ W + bias
    mfma_gemm<<<782, 256, 0, stream>>>(Sb, Wfrag, bias, out);
}

// Round 10
// 226.827 us; speedup vs baseline: 1.0865x; 1.0865x over previous
//
#include <hip/hip_runtime.h>
#include <hip/hip_fp16.h>

#define NN 50000
#define NE 800000
#define D  96
#define NB_SCAN 196   // ceil(NN/256)
#define N4 (NN * D / 4)
#define CB4 ((N4 + 255) / 256)
#define WFRAG_BLKS 5  // ceil(18*64/256)
#define EMAX (NE + 4 * NN)          // padded edge capacity (1.0M, pad-to-4)

typedef unsigned int   uint32;
typedef unsigned short uint16;
typedef _Float16 v8h __attribute__((ext_vector_type(8)));  // 8 f16 (4 VGPRs)
typedef float  v4f __attribute__((ext_vector_type(4)));    // MFMA accumulator
typedef unsigned int v2u __attribute__((ext_vector_type(2)));
typedef unsigned int v4u __attribute__((ext_vector_type(4)));
typedef float v2f __attribute__((ext_vector_type(2)));

__device__ inline __half2 u2h(uint32 u) { union { uint32 u; __half2 h; } c; c.u = u; return c.h; }
__device__ inline uint32 h2u(__half2 h) { union { uint32 u; __half2 h; } c; c.h = h; return c.u; }

// ---- fused prep: H->f16 | zero counts | W->B-frag layout (f16) ----
__global__ void prep(const float4* __restrict__ H, ushort4* __restrict__ Hh,
                     const float* __restrict__ W, uint16* __restrict__ Wfrag,
                     int* __restrict__ counts) {
    int b = blockIdx.x;
    int t = threadIdx.x;
    if (b < CB4) {
        int i = b * 256 + t;
        if (i < N4) {
            float4 v = H[i];
            ushort4 o;
            o.x = __half_raw(__float2half(v.x)).x;
            o.y = __half_raw(__float2half(v.y)).x;
            o.z = __half_raw(__float2half(v.z)).x;
            o.w = __half_raw(__float2half(v.w)).x;
            Hh[i] = o;
        }
    } else if (b < CB4 + NB_SCAN) {
        int i = (b - CB4) * 256 + t;
        if (i < NN) counts[i] = 0;
    } else {
        int idx = (b - CB4 - NB_SCAN) * 256 + t;   // 0..1151 = bt*64+lane
        if (idx < 18 * 64) {
            int bt = idx >> 6, lane = idx & 63;
            int nt = bt / 3, kc = bt % 3;
            int col = nt * 16 + (lane & 15);
            int kbase = kc * 32 + (lane >> 4) * 8;
            uint16 tmp[8];
            #pragma unroll
            for (int j = 0; j < 8; ++j)
                tmp[j] = __half_raw(__float2half(W[(kbase + j) * D + col])).x;
            uint32* dst = (uint32*)(Wfrag + ((size_t)bt * 64 + lane) * 8);
            const uint32* src = (const uint32*)tmp;
            #pragma unroll
            for (int j = 0; j < 4; ++j) dst[j] = src[j];
        }
    }
}

// ---------------- CSR build (two-phase, slot-based, 4-padded rows) ----------
// 2 edges per thread.
__global__ void hist_slots(const int* __restrict__ rows, int* __restrict__ counts,
                           int* __restrict__ slot) {
    int base = (blockIdx.x * blockDim.x + threadIdx.x) * 2;
    if (base < NE) {
        v2u rr = *(const v2u*)(rows + base);
        slot[base]     = atomicAdd(&counts[rr.x], 1);
        slot[base + 1] = atomicAdd(&counts[rr.y], 1);
    }
}

__global__ void scan_p1(const int* __restrict__ counts, int* __restrict__ partials) {
    __shared__ int red[256];
    int t = threadIdx.x;
    int i = blockIdx.x * 256 + t;
    red[t] = (i < NN) ? ((counts[i] + 3) & ~3) : 0;   // padded counts (x4)
    __syncthreads();
    for (int off = 128; off > 0; off >>= 1) {
        if (t < off) red[t] += red[t + off];
        __syncthreads();
    }
    if (t == 0) partials[blockIdx.x] = red[0];
}

// Also zeroes the <=3 pad slots per row (replaces the 4MB edge-array memset).
__global__ void scan_p23(const int* __restrict__ counts, const int* __restrict__ partials,
                         int* __restrict__ row_ptr, uint32* __restrict__ edges) {
    __shared__ int pp[256];
    __shared__ int sh[256];
    int t = threadIdx.x;
    pp[t] = (t < NB_SCAN) ? partials[t] : 0;
    __syncthreads();
    for (int off = 1; off < 256; off <<= 1) {
        int u = (t >= off) ? pp[t - off] : 0;
        __syncthreads();
        pp[t] += u;
        __syncthreads();
    }
    int blk_off = (blockIdx.x == 0) ? 0 : pp[blockIdx.x - 1];
    int i = blockIdx.x * 256 + t;
    int c = (i < NN) ? counts[i] : 0;
    int v = (c + 3) & ~3;                              // padded count (x4)
    sh[t] = v;
    __syncthreads();
    for (int off = 1; off < 256; off <<= 1) {
        int u = (t >= off) ? sh[t - off] : 0;
        __syncthreads();
        sh[t] += u;
        __syncthreads();
    }
    int excl = sh[t] - v + blk_off;
    if (i < NN) {
        row_ptr[i] = excl;
        for (int k = c; k < v; ++k) edges[excl + k] = 0u;   // pad slots -> zero
    }
    if (i == NN - 1) row_ptr[NN] = excl + v;
}

// edge = col (low 16) | f16(val) (high 16); p = row_ptr[row] + slot. 2/thread.
__global__ void fill_edges(const int* __restrict__ rows, const int* __restrict__ cols,
                           const float* __restrict__ vals, const int* __restrict__ row_ptr,
                           const int* __restrict__ slot, uint32* __restrict__ edges) {
    int base = (blockIdx.x * blockDim.x + threadIdx.x) * 2;
    if (base < NE) {
        v2u rr = *(const v2u*)(rows + base);
        v2u cc = *(const v2u*)(cols + base);
        v2f vv = *(const v2f*)(vals + base);
        v2u ss = *(const v2u*)(slot + base);
        __half_raw h0 = __half_raw(__float2half(vv.x));
        __half_raw h1 = __half_raw(__float2half(vv.y));
        edges[row_ptr[rr.x] + ss.x] = (cc.x & 0xFFFF) | ((uint32)h0.x << 16);
        edges[row_ptr[rr.y] + ss.y] = (cc.y & 0xFFFF) | ((uint32)h1.x << 16);
    }
}

// ---- f16 gather core: a01/a23 (f16x2) += val * X[col, lane-chunk] ----------
// 32 lanes/row, lanes 0..23 own 4 feats (8B gathers). Rows padded to 4 edges;
// main loop x16, 8-tail, 4-tail. sched_barrier(0) between the gather block and
// the FMA block forces ALL gathers to issue before any consumer -> 16 (resp. 8)
// loads genuinely in flight (round-8 verified: -5us vs without).
__device__ inline void gather_f16(const uint32* __restrict__ edges, int s, int e,
                                  const char* __restrict__ lanep,
                                  __half2& a01, __half2& a23) {
    a01 = u2h(0u); a23 = u2h(0u);
    int i = s;
    for (; i + 15 < e; i += 16) {
        v4u e0 = *(const v4u*)(edges + i);
        v4u e1 = *(const v4u*)(edges + i + 4);
        v4u e2 = *(const v4u*)(edges + i + 8);
        v4u e3 = *(const v4u*)(edges + i + 12);
        uint32 ee[16] = {e0.x,e0.y,e0.z,e0.w, e1.x,e1.y,e1.z,e1.w,
                         e2.x,e2.y,e2.z,e2.w, e3.x,e3.y,e3.z,e3.w};
        v2u xx[16];
        #pragma unroll
        for (int j = 0; j < 16; ++j)
            xx[j] = *(const v2u*)(lanep + (ee[j] & 0xFFFFu) * 192u);
        __builtin_amdgcn_sched_barrier(0);   // all 16 gathers issued first
        #pragma unroll
        for (int j = 0; j < 16; ++j) {
            __half2 vv = u2h(__builtin_amdgcn_perm(ee[j], ee[j], 0x03020302u));
            a01 = __hfma2(vv, u2h(xx[j].x), a01);
            a23 = __hfma2(vv, u2h(xx[j].y), a23);
        }
    }
    for (; i + 7 < e; i += 8) {
        v4u ea = *(const v4u*)(edges + i);
        v4u eb = *(const v4u*)(edges + i + 4);
        uint32 ee[8] = {ea.x, ea.y, ea.z, ea.w, eb.x, eb.y, eb.z, eb.w};
        v2u xx[8];
        #pragma unroll
        for (int j = 0; j < 8; ++j)
            xx[j] = *(const v2u*)(lanep + (ee[j] & 0xFFFFu) * 192u);
        __builtin_amdgcn_sched_barrier(0);   // all 8 gathers issued first
        #pragma unroll
        for (int j = 0; j < 8; ++j) {
            __half2 vv = u2h(__builtin_amdgcn_perm(ee[j], ee[j], 0x03020302u));
            a01 = __hfma2(vv, u2h(xx[j].x), a01);
            a23 = __hfma2(vv, u2h(xx[j].y), a23);
        }
    }
    if (i < e) {
        v4u ea = *(const v4u*)(edges + i);
        uint32 ee[4] = {ea.x, ea.y, ea.z, ea.w};
        v2u xx[4];
        #pragma unroll
        for (int j = 0; j < 4; ++j)
            xx[j] = *(const v2u*)(lanep + (ee[j] & 0xFFFFu) * 192u);
        #pragma unroll
        for (int j = 0; j < 4; ++j) {
            __half2 vv = u2h(__builtin_amdgcn_perm(ee[j], ee[j], 0x03020302u));
            a01 = __hfma2(vv, u2h(xx[j].x), a01);
            a23 = __hfma2(vv, u2h(xx[j].y), a23);
        }
    }
}

// ---- pure SpMM: Yh = f16( sum val * Xh[col] ); store is free (acc is f16) --
__global__ void spmm(const int* __restrict__ row_ptr, const uint32* __restrict__ edges,
                     const uint16* __restrict__ Xh, uint16* __restrict__ Yh) {
    int tid  = threadIdx.x;
    int lane = tid & 31;
    int g    = tid >> 5;
    int r = blockIdx.x * 8 + g;
    if (r >= NN) return;
    if (lane >= 24) return;

    const char* lanep = (const char*)Xh + lane * 8;

    int s = row_ptr[r];
    int e = row_ptr[r + 1];
    __half2 a01, a23;
    gather_f16(edges, s, e, lanep, a01, a23);

    v2u o; o.x = h2u(a01); o.y = h2u(a23);
    *((v2u*)(Yh + (size_t)r * D) + lane) = o;
}

// ---- fused pass 3: Sh = f16( 12*U1 - 40*U2 + 32 * P U2 ) -------------------
__global__ void spmm_fuse(const int* __restrict__ row_ptr, const uint32* __restrict__ edges,
                          const uint16* __restrict__ U1, const uint16* __restrict__ U2,
                          uint16* __restrict__ Sh) {
    int tid  = threadIdx.x;
    int lane = tid & 31;
    int g    = tid >> 5;
    int r = blockIdx.x * 8 + g;
    if (r >= NN) return;
    if (lane >= 24) return;

    const char* lanep = (const char*)U2 + lane * 8;

    int s = row_ptr[r];
    int e = row_ptr[r + 1];
    __half2 a01, a23;
    gather_f16(edges, s, e, lanep, a01, a23);

    v2u w1 = *((const v2u*)(U1 + (size_t)r * D) + lane);
    v2u w2 = *(const v2u*)(lanep + (uint32)r * 192u);
    float2 ax = __half22float2(a01),      ay = __half22float2(a23);
    float2 p01 = __half22float2(u2h(w1.x)), p23 = __half22float2(u2h(w1.y));
    float2 q01 = __half22float2(u2h(w2.x)), q23 = __half22float2(u2h(w2.y));

    float2 s01, s23;
    s01.x = 12.f*p01.x - 40.f*q01.x + 32.f*ax.x;
    s01.y = 12.f*p01.y - 40.f*q01.y + 32.f*ax.y;
    s23.x = 12.f*p23.x - 40.f*q23.x + 32.f*ay.x;
    s23.y = 12.f*p23.y - 40.f*q23.y + 32.f*ay.y;

    v2u o;                                   // f16 output (v_cvt_pkrtz x2)
    o.x = h2u(__float22half2_rn(s01));
    o.y = h2u(__float22half2_rn(s23));
    *((v2u*)(Sh + (size_t)r * D) + lane) = o;
}

// ---- out = Sh @ W + bias via f16 MFMA; one wave per 16-row strip -----------
__global__ void mfma_gemm(const uint16* __restrict__ Sh, const uint16* __restrict__ Wfrag,
                          const float* __restrict__ bias, float* __restrict__ out) {
    int tid   = threadIdx.x;
    int lane  = tid & 63;
    int wv    = blockIdx.x * (blockDim.x >> 6) + (tid >> 6);
    int nwv   = gridDim.x * (blockDim.x >> 6);
    int col   = lane & 15;
    int quad  = lane >> 4;

    v8h wf[6][3];
    #pragma unroll
    for (int nt = 0; nt < 6; ++nt)
        #pragma unroll
        for (int kc = 0; kc < 3; ++kc)
            wf[nt][kc] = ((const v8h*)Wfrag)[(nt * 3 + kc) * 64 + lane];

    float bi[6];
    #pragma unroll
    for (int nt = 0; nt < 6; ++nt) bi[nt] = bias[nt * 16 + col];

    for (int s = wv; s < NN / 16; s += nwv) {
        int r0 = s * 16;
        const uint16* arow = Sh + (size_t)(r0 + col) * D + quad * 8;
        v8h a0 = *((const v8h*)(arow));
        v8h a1 = *((const v8h*)(arow + 32));
        v8h a2 = *((const v8h*)(arow + 64));
        v4f acc[6];
        #pragma unroll
        for (int nt = 0; nt < 6; ++nt) {
            v4f c = {0.f, 0.f, 0.f, 0.f};
            c = __builtin_amdgcn_mfma_f32_16x16x32_f16(a0, wf[nt][0], c, 0, 0, 0);
            c = __builtin_amdgcn_mfma_f32_16x16x32_f16(a1, wf[nt][1], c, 0, 0, 0);
            c = __builtin_amdgcn_mfma_f32_16x16x32_f16(a2, wf[nt][2], c, 0, 0, 0);
            acc[nt] = c;
        }
        #pragma unroll
        for (int nt = 0; nt < 6; ++nt) {
            float* o = out + (size_t)(r0 + quad * 4) * D + nt * 16 + col;
            __builtin_nontemporal_store(acc[nt][0] + bi[nt], o + 0 * D);
            __builtin_nontemporal_store(acc[nt][1] + bi[nt], o + 1 * D);
            __builtin_nontemporal_store(acc[nt][2] + bi[nt], o + 2 * D);
            __builtin_nontemporal_store(acc[nt][3] + bi[nt], o + 3 * D);
        }
    }
}

extern "C" void kernel_launch(void* const* d_in, const int* in_sizes, int n_in,
                              void* d_out, int out_size, void* d_ws, size_t ws_size,
                              hipStream_t stream) {
    const int*   rows = (const int*)d_in[0];
    const int*   cols = (const int*)d_in[1];
    const float* vals = (const float*)d_in[2];
    const float* H    = (const float*)d_in[3];
    const float* W    = (const float*)d_in[4];
    const float* bias = (const float*)d_in[5];
    float* out = (float*)d_out;

    char* ws = (char*)d_ws;
    uint16* Hh       = (uint16*)ws;  ws += (size_t)NN * D * 2;   // 9.6 MB (f16)
    uint16* U1h      = (uint16*)ws;  ws += (size_t)NN * D * 2;   // f16
    uint16* U2h      = (uint16*)ws;  ws += (size_t)NN * D * 2;   // f16; slot aliases here
    uint16* Sh       = (uint16*)ws;  ws += (size_t)NN * D * 2;   // f16 (MFMA input)
    uint32* edges    = (uint32*)ws;  ws += (size_t)EMAX * 4;     // 4.0 MB padded
    uint16* Wfrag    = (uint16*)ws;  ws += (size_t)18 * 64 * 8 * 2;
    int*    counts   = (int*)ws;     ws += (size_t)NN * 4;
    int*    row_ptr  = (int*)ws;     ws += (size_t)(NN + 1) * 4;
    int*    partials = (int*)ws;     ws += 256 * 4;
    int*    slot     = (int*)U2h;    // dead before spmm writes U2h

    const int eb2 = (NE / 2 + 255) / 256;   // 2 edges/thread

    prep<<<CB4 + NB_SCAN + WFRAG_BLKS, 256, 0, stream>>>(
        (const float4*)H, (ushort4*)Hh, W, Wfrag, counts);
    hist_slots<<<eb2, 256, 0, stream>>>(rows, counts, slot);
    scan_p1<<<NB_SCAN, 256, 0, stream>>>(counts, partials);
    scan_p23<<<NB_SCAN, 256, 0, stream>>>(counts, partials, row_ptr, edges);
    fill_edges<<<eb2, 256, 0, stream>>>(rows, cols, vals, row_ptr, slot, edges);

    const int sb = (NN + 7) / 8;   // 6250 blocks, 8 rows each

    // U1 = P H,  U2 = P U1,  Sh = 12U1 - 40U2 + 32 P U2  (= T0+T1+T2+T3)
    spmm<<<sb, 256, 0, stream>>>(row_ptr, edges, Hh,  U1h);
    spmm<<<sb, 256, 0, stream>>>(row_ptr, edges, U1h, U2h);
    spmm_fuse<<<sb, 256, 0, stream>>>(row_ptr, edges, U1h, U2h, Sh);
    // out = Sh @ W + bias
    mfma_gemm<<<782, 256, 0, stream>>>(Sh, Wfrag, bias, out);
}